// Round 3
// baseline (137383.948 us; speedup 1.0000x reference)
//
#include <hip/hip_runtime.h>

// ============================================================================
// Persistent pipelined LSTM-with-projection, fp32, MI355X (gfx950).
//
// R3 change vs R2: the 64-way projection reduce no longer round-trips
// [P x B] partials through agent-scope memory (17.5 GB of fence-flushed
// writes = the whole 102 ms, per rocprof WRITE_SIZE). Instead each WG
// broadcasts its ACT slice (4 KB) and computes its own 4-wide p-slice of
// h = act . Whr^T by streaming all acts once through LDS. Agent-released
// writes per WG-step: 65 KB -> 5 KB. Also: gate GEMM split into x-half
// (ready early) and h-half (critical path), and flag spins are wave-0-only.
//
// grid = 256 WGs = 4 layers x 64 cell-slices (16 cells each), 1 WG/CU.
// Gate weights stay LDS-resident all kernel (k-major, swizzled).
// ============================================================================

#define B_    64
#define T_    1024
#define P_    256
#define H_    1024
#define L_    4
#define G4_   4096
#define NTHR  256
#define WWIN  8                     // h ring slots (power of two)
#define HSLOT (P_ * B_)             // 16384 floats per slot, layout [p][b]

#define LDS_W     (512 * 64)        // 131072 B, k-major, swizzled rows
#define LDS_XH    4096              // 16 KB: GEMM staging; proj arena (w/ ACT)
#define LDS_ACT   1024              // act [16 cells][64 b]
#define LDS_BIAS  64
#define LDS_FLOATS (LDS_W + LDS_XH + LDS_ACT + LDS_BIAS)
#define LDS_BYTES  (LDS_FLOATS * 4) // 151808 B

// projection arena (floats, offsets from XH base; spills into ACT region,
// which is dead by then; BIAS at +5120 untouched)
#define PA_CH  36                   // padded row: 32 j + 4
#define PA_BUF (64 * PA_CH)         // 2304 floats per act chunk buffer
#define PW_OFF (2 * PA_BUF)         // 4608: two Whr chunk buffers of 144
#define PW_BUF (4 * PA_CH)          // 144

#define ACT_FLOATS ((size_t)L_ * H_ * B_)        // 1 MB act broadcast bufs
#define HBUF_FLOATS ((size_t)L_ * WWIN * HSLOT)  // 2 MB h ring

struct alignas(16) F4 { float f[4]; };

__device__ __forceinline__ float fsig(float x) {
  float e = __expf(-x);                       // saturation-safe
  return __builtin_amdgcn_rcpf(1.0f + e);
}
__device__ __forceinline__ float ftanh(float x) {
  float ax = fabsf(x);
  float e  = __expf(-2.0f * ax);              // in (0,1] -> no overflow/NaN
  float r  = (1.0f - e) * __builtin_amdgcn_rcpf(1.0f + e);
  return copysignf(r, x);
}
// sum over lane quads {4q..4q+3}: butterfly xor1 then xor2 (quad_perm DPP)
__device__ __forceinline__ float qsum(float v) {
  v += __int_as_float(__builtin_amdgcn_update_dpp(
        0, __float_as_int(v), 0xB1, 0xF, 0xF, false)); // [1,0,3,2]
  v += __int_as_float(__builtin_amdgcn_update_dpp(
        0, __float_as_int(v), 0x4E, 0xF, 0xF, false)); // [2,3,0,1]
  return v;
}
// wave 0 polls 64 flags; everyone else parks at the barrier (4x less spin
// traffic to the coherence point than all-wave polling).
__device__ __forceinline__ void wait1(int* f, int tid, int target) {
  if (tid < 64) {
    while (true) {
      int v = __hip_atomic_load(&f[tid], __ATOMIC_RELAXED, __HIP_MEMORY_SCOPE_AGENT);
      if (__ballot(v < target) == 0ull) break;
      __builtin_amdgcn_s_sleep(2);
    }
  }
  __syncthreads();
}

extern "C" __global__ void __launch_bounds__(NTHR, 1)
lstm_persistent(const float* __restrict__ y,
                const float* __restrict__ Wih,
                const float* __restrict__ Whh,
                const float* __restrict__ bih,
                const float* __restrict__ bhh,
                const float* __restrict__ Whr,
                const int*   __restrict__ mslp,
                float*       __restrict__ out,
                float*       __restrict__ hbuf,
                float*       __restrict__ actg,
                int*         __restrict__ hflag,
                int*         __restrict__ pflag)
{
  extern __shared__ float lds[];
  float* Ws   = lds;
  float* XH   = lds + LDS_W;
  float* ACT  = XH + LDS_XH;
  float* BIAS = ACT + LDS_ACT;
  float* PRJ  = XH;                 // proj arena: 4896 floats over XH+ACT

  // XCD-pair remap: layer l on XCDs {2l,2l+1} if blocks round-robin bid%8.
  const int bid = blockIdx.x;
  const int l   = (bid & 7) >> 1;
  const int w   = ((bid & 1)) + 2 * (bid >> 3);   // 0..63, bijective
  const int J0  = w * 16;
  const int tid  = threadIdx.x;
  const int lane = tid & 63;
  const int msl  = mslp[0];

  // ---- one-time: gate-weight slice (k-major, swizzled) + bias into LDS ----
  {
    const float* wih_l = Wih + (size_t)l * G4_ * P_;
    const float* whh_l = Whh + (size_t)l * G4_ * P_;
    for (int it = 0; it < 32; ++it) {
      int idx4 = tid + NTHR * it;            // 8192 F4 total
      int r    = idx4 >> 7;                  // 0..63, r = 4*cell + gate
      int k4   = (idx4 & 127) << 2;          // 0..508
      int g = r & 3, j = r >> 2;
      int grow = g * H_ + J0 + j;            // torch gate order i,f,g,o
      F4 v;
      if (k4 < 256) v = *(const F4*)&wih_l[(size_t)grow * P_ + k4];
      else          v = *(const F4*)&whh_l[(size_t)grow * P_ + (k4 - 256)];
#pragma unroll
      for (int i = 0; i < 4; ++i)
        Ws[(size_t)(k4 + i) * 64 + (r ^ (4 * (i & 1)))] = v.f[i];
    }
    if (tid < 64) {
      int g = tid & 3, j = tid >> 2;
      int grow = g * H_ + J0 + j;
      BIAS[tid] = bih[l * G4_ + grow] + bhh[l * G4_ + grow];
    }
  }
  __syncthreads();

  // ---- thread mappings ----------------------------------------------------
  const int w4   = tid >> 6;            // wave 0..3
  const int c16  = lane >> 2;           // 0..15
  const int ksub = lane & 3;            // k-split lane within quad
  const int lr   = (w4 << 1) | (c16 >> 3);   // 0..7 -> rows 8lr..8lr+7
  const int lb   = c16 & 7;                  // 0..7 -> b 8lb..8lb+7
  const int swz  = 4 * (ksub & 1);           // W row swizzle (kl&1 == ksub&1)
  // GEMM staging (transpose path, layer-0 y):
  const int sb0 = tid >> 3, skq = tid & 7, skl = skq << 2;
  // GEMM staging (fast path, h ring [p][b]):
  const int kidx = tid >> 3, bq = tid & 7;
  // act repack / proj staging:
  const int jqr = tid >> 6, b_r = tid & 63;
  // proj compute: wave w4 owns b in [16*w4, 16*w4+16), 4 p's across lane>>4
  const int b_p = (w4 << 4) | (tid & 15);
  const int pw  = (tid >> 4) & 3;

  float* hsrc = hbuf + (size_t)l * (WWIN * HSLOT);
  const float* hprv = (l > 0) ? (hbuf + (size_t)(l - 1) * (WWIN * HSLOT)) : hbuf;
  F4* AG4 = (F4*)(actg + (size_t)l * H_ * B_);   // [jq 0..255][b 0..63] of F4

  float biasr[8];
#pragma unroll
  for (int i = 0; i < 8; ++i) biasr[i] = BIAS[8 * lr + i];

  float cst[2][2] = {{0.f, 0.f}, {0.f, 0.f}};  // c for (cell 2lr+m, b 8lb+2ksub+n)

  for (int t = 0; t < T_; ++t) {
    float acc[8][8];
#pragma unroll
    for (int i = 0; i < 8; ++i)
#pragma unroll
      for (int jx = 0; jx < 8; ++jx) acc[i][jx] = 0.f;

    // stage one 32k x 64b chunk into dst, layout X[k][ b ^ (k&28) ^ 4(k&1) ]
    auto stage = [&](int cc, float* dst) {
      const int koff = (cc & 7) << 5;
      if (l == 0 && cc < 8) {           // y is [b][T][P]: transpose path
        F4 ra  = *(const F4*)(y + ((size_t)sb0 * T_ + t) * P_ + koff + skl);
        F4 rb4 = *(const F4*)(y + ((size_t)(sb0 + 32) * T_ + t) * P_ + koff + skl);
#pragma unroll
        for (int i2 = 0; i2 < 4; ++i2) {
          const int sw = (skq << 2) ^ (4 * (i2 & 1));
          dst[(skl + i2) * 64 + (sb0 ^ sw)]        = ra.f[i2];
          dst[(skl + i2) * 64 + ((sb0 + 32) ^ sw)] = rb4.f[i2];
        }
      } else {                          // h ring is [slot][p][b]: direct F4
        const float* src = (cc < 8) ? hprv + (size_t)(t & (WWIN - 1)) * HSLOT
                                    : hsrc + (size_t)((t - 1) & (WWIN - 1)) * HSLOT;
        const float* pb = src + (size_t)(koff + kidx) * 64 + 4 * bq;
        F4 a = *(const F4*)(pb);
        F4 b = *(const F4*)(pb + 32);
        const int sx = (kidx & 28) ^ (4 * (kidx & 1));
        *(F4*)&dst[kidx * 64 + ((4 * bq) ^ sx)]      = a;
        *(F4*)&dst[kidx * 64 + ((4 * bq + 32) ^ sx)] = b;
      }
    };
    auto gemm_chunk = [&](int cc) {
      const float* buf = XH + ((cc & 1) << 11);
      const int kb = cc << 5;
#pragma unroll
      for (int jj = 0; jj < 8; ++jj) {
        const int kl = 4 * jj + ksub;                   // this lane's k
        const float* wrow = Ws + (size_t)(kb + kl) * 64;
        F4 wlo = *(const F4*)&wrow[(8 * lr) ^ swz];
        F4 whi = *(const F4*)&wrow[(8 * lr + 4) ^ swz];
        const int sx = (4 * jj) ^ swz;                  // kl&28 = 4*jj
        const float* xrow = buf + kl * 64;
        F4 xlo = *(const F4*)&xrow[(8 * lb) ^ sx];
        F4 xhi = *(const F4*)&xrow[(8 * lb + 4) ^ sx];
#pragma unroll
        for (int i = 0; i < 4; ++i)
#pragma unroll
          for (int jx = 0; jx < 4; ++jx) {
            acc[i][jx]         = fmaf(wlo.f[i], xlo.f[jx], acc[i][jx]);
            acc[i][jx + 4]     = fmaf(wlo.f[i], xhi.f[jx], acc[i][jx + 4]);
            acc[i + 4][jx]     = fmaf(whi.f[i], xlo.f[jx], acc[i + 4][jx]);
            acc[i + 4][jx + 4] = fmaf(whi.f[i], xhi.f[jx], acc[i + 4][jx + 4]);
          }
      }
    };

    // ---- x-half of gate GEMM (input ready one pipeline stage early) -------
    if (l > 0) { wait1(hflag + (l - 1) * 64, tid, t); __threadfence(); }
    stage(0, XH);
    __syncthreads();
    for (int cc = 0; cc < 8; ++cc) {
      if (cc < 7) stage(cc + 1, XH + (((cc + 1) & 1) << 11));
      gemm_chunk(cc);
      __syncthreads();
    }
    // ---- h-half (the recurrent critical path) -----------------------------
    if (t > 0) {
      wait1(hflag + l * 64, tid, t - 1); __threadfence();
      stage(8, XH);
      __syncthreads();
      for (int cc = 8; cc < 16; ++cc) {
        if (cc < 15) stage(cc + 1, XH + (((cc + 1) & 1) << 11));
        gemm_chunk(cc);
        __syncthreads();
      }
    }

    // ---- combine k-split partials across lane quads (VALU-only) -----------
#pragma unroll
    for (int i = 0; i < 8; ++i)
#pragma unroll
      for (int jx = 0; jx < 8; ++jx) acc[i][jx] = qsum(acc[i][jx]);

    // ---- activations + cell update; own cols are 2ksub,2ksub+1 ------------
#pragma unroll
    for (int m = 0; m < 2; ++m)
#pragma unroll
      for (int n = 0; n < 2; ++n) {
#define MUX(I) ((ksub & 2) ? ((ksub & 1) ? acc[I][6 + n] : acc[I][4 + n])  \
                           : ((ksub & 1) ? acc[I][2 + n] : acc[I][0 + n]))
        float vi = MUX(4 * m + 0) + biasr[4 * m + 0];
        float vf = MUX(4 * m + 1) + biasr[4 * m + 1];
        float vg = MUX(4 * m + 2) + biasr[4 * m + 2];
        float vo = MUX(4 * m + 3) + biasr[4 * m + 3];
#undef MUX
        float ig = fsig(vi), fg = fsig(vf), gg = ftanh(vg), og = fsig(vo);
        float cn = fmaf(fg, cst[m][n], ig * gg);
        cst[m][n] = cn;
        ACT[(2 * lr + m) * 64 + (8 * lb + 2 * ksub + n)] = og * ftanh(cn);
      }
    __syncthreads();

    // ---- broadcast acts: repack ACT[16][64] -> global [jq][b][4], 4 KB ----
    {
      F4 av;
#pragma unroll
      for (int u = 0; u < 4; ++u) av.f[u] = ACT[(4 * jqr + u) * 64 + b_r];
      AG4[(size_t)(4 * w + jqr) * 64 + b_r] = av;
    }
    __threadfence();     // release own act writes (all threads: own vm drain)
    __syncthreads();
    if (tid == 0)
      __hip_atomic_store(&pflag[l * 64 + w], t, __ATOMIC_RELAXED, __HIP_MEMORY_SCOPE_AGENT);

    // ---- projection: h[b][4w+pw] = sum_j act[j][b] * Whr[4w+pw][j] --------
    wait1(pflag + l * 64, tid, t);
    __threadfence();     // acquire all acts

    auto stage_a = [&](int ch, float* abuf) {
#pragma unroll
      for (int u = 0; u < 2; ++u) {
        const int jql = (jqr << 1) | u;                  // 0..7
        F4 v = AG4[(size_t)(8 * ch + jql) * 64 + b_r];
        *(F4*)&abuf[b_r * PA_CH + 4 * jql] = v;          // [b][jc], pad 36
      }
    };
    auto stage_w = [&](int ch, float* wbuf) {
      if (tid < 32) {
        const int pws = tid >> 3, jql = tid & 7;
        F4 v = *(const F4*)(Whr + ((size_t)(l * P_ + 4 * w + pws)) * H_
                            + 32 * ch + 4 * jql);
        *(F4*)&wbuf[pws * PA_CH + 4 * jql] = v;
      }
    };

    float s = 0.f;
    stage_a(0, PRJ); stage_w(0, PRJ + PW_OFF);
    __syncthreads();
    for (int ch = 0; ch < 32; ++ch) {
      const int cur = ch & 1, nxt = cur ^ 1;
      if (ch < 31) {
        stage_a(ch + 1, PRJ + nxt * PA_BUF);
        stage_w(ch + 1, PRJ + PW_OFF + nxt * PW_BUF);
      }
      const float* ab = PRJ + cur * PA_BUF + b_p * PA_CH;
      const float* wb = PRJ + PW_OFF + cur * PW_BUF + pw * PA_CH;
#pragma unroll
      for (int jj = 0; jj < 8; ++jj) {
        F4 a  = *(const F4*)&ab[4 * jj];
        F4 wv = *(const F4*)&wb[4 * jj];
        s = fmaf(a.f[0], wv.f[0], s);
        s = fmaf(a.f[1], wv.f[1], s);
        s = fmaf(a.f[2], wv.f[2], s);
        s = fmaf(a.f[3], wv.f[3], s);
      }
      __syncthreads();
    }

    // ---- emit h (ring [slot][p][b]) + output ------------------------------
    if (l < 3) wait1(hflag + (l + 1) * 64, tid, t - WWIN);   // ring back-pressure
    hsrc[(size_t)(t & (WWIN - 1)) * HSLOT + (size_t)(4 * w + pw) * 64 + b_p] = s;
    if (l == 3 && t >= msl)
      out[((size_t)b_p * (T_ - msl) + (t - msl)) * P_ + 4 * w + pw] = s;
    __threadfence();     // release h (each thread drains own writes)
    __syncthreads();
    if (tid == 0)
      __hip_atomic_store(&hflag[l * 64 + w], t, __ATOMIC_RELAXED, __HIP_MEMORY_SCOPE_AGENT);
  }
}

extern "C" void kernel_launch(void* const* d_in, const int* in_sizes, int n_in,
                              void* d_out, int out_size, void* d_ws, size_t ws_size,
                              hipStream_t stream) {
  const float* y   = (const float*)d_in[0];
  const float* Wih = (const float*)d_in[1];
  const float* Whh = (const float*)d_in[2];
  const float* bih = (const float*)d_in[3];
  const float* bhh = (const float*)d_in[4];
  const float* Whr = (const float*)d_in[5];
  const int*   msl = (const int*)d_in[6];
  float* out = (float*)d_out;

  // ws: [flags 4KB][act broadcast 1MB][h ring 2MB]  (~3 MB total)
  char*  ws    = (char*)d_ws;
  int*   flags = (int*)ws;
  float* actg  = (float*)(ws + 4096);
  float* hbuf  = (float*)(ws + 4096 + ACT_FLOATS * sizeof(float));

  hipMemsetAsync(flags, 0xFF, 4096, stream);   // epoch counters start at -1

  hipFuncSetAttribute(reinterpret_cast<const void*>(&lstm_persistent),
                      hipFuncAttributeMaxDynamicSharedMemorySize, LDS_BYTES);

  lstm_persistent<<<dim3(L_ * 64), dim3(NTHR), LDS_BYTES, stream>>>(
      y, Wih, Whh, bih, bhh, Whr, msl, out,
      hbuf, actg, flags /*hflag*/, flags + 256 /*pflag*/);
}

// Round 5
// 64677.869 us; speedup vs baseline: 2.1241x; 2.1241x over previous
//
#include <hip/hip_runtime.h>

// ============================================================================
// Persistent pipelined LSTM-with-projection, fp32, MI355X (gfx950).
//
// R5 = R3 structure (last PASSING kernel) with its __threadfence()s (agent
// fence = buffer_wbl2+inv full-L2 sweep; 90% of R3's 137ms, VALUBusy 9%)
// replaced by compiler-emitted per-access coherence:
//   - cross-WG data (h ring, act broadcast) via __hip_atomic_load/store
//     (RELAXED, AGENT) -> compiler emits the right sc bits AND tracks vmcnt
//     (R4's hand-rolled asm + manual vmcnt(3) counting produced undefined
//     registers -> absmax 1.7e8; compiler VMEM ops break manual counts).
//   - release = s_waitcnt vmcnt(0) drain (conservative, no counting) +
//     relaxed agent flag store. Valid: all communicated stores are
//     write-through-scoped, so no dirty L2 lines need wbl2.
//   - latency hiding: issue loads into locals -> compute -> commit to LDS;
//     compiler sinks its waitcnt behind the FMA block.
// Read-only inputs (y, Wih, Whh, bias, Whr) stay plain cached loads.
//
// grid = 256 WGs = 4 layers x 64 cell-slices (16 cells), 1 WG/CU; gate W
// LDS-resident (k-major swizzled); 8x8 reg tile GEMM, 4-way k-split + DPP
// quad reduce; acts broadcast (4KB/WG-step); h ring 8 slots, [slot][p][b].
// ============================================================================

#define B_    64
#define T_    1024
#define P_    256
#define H_    1024
#define L_    4
#define G4_   4096
#define NTHR  256
#define WWIN  8                     // h ring slots (power of two)
#define HSLOT (P_ * B_)             // 16384 floats per slot, layout [p][b]

#define LDS_W     (512 * 64)        // 131072 B, k-major, swizzled rows
#define LDS_XH    4096              // 16 KB: GEMM staging; proj arena (w/ ACT)
#define LDS_ACT   1024              // act [16 cells][64 b]
#define LDS_FLOATS (LDS_W + LDS_XH + LDS_ACT)
#define LDS_BYTES  (LDS_FLOATS * 4) // 151552 B

// projection arena overlays XH+ACT (both dead during proj): 4896 <= 5120
#define PA_CH  36                   // padded row: 32 j + 4
#define PA_BUF (64 * PA_CH)         // 2304 floats per act chunk buffer
#define PW_OFF (2 * PA_BUF)         // 4608: two Whr chunk buffers of 144
#define PW_BUF (4 * PA_CH)          // 144

#define ACT_FLOATS ((size_t)L_ * H_ * B_)        // 1 MB act broadcast bufs

struct alignas(16) F4 { float f[4]; };

// ---- cross-WG data movement: compiler-tracked agent-scope accesses ---------
__device__ __forceinline__ float lda(const float* p) {
  return __hip_atomic_load(p, __ATOMIC_RELAXED, __HIP_MEMORY_SCOPE_AGENT);
}
__device__ __forceinline__ void sta(float* p, float v) {
  __hip_atomic_store(p, v, __ATOMIC_RELAXED, __HIP_MEMORY_SCOPE_AGENT);
}
__device__ __forceinline__ void drain_vm() {   // conservative release: drain all
  asm volatile("s_waitcnt vmcnt(0)" ::: "memory");
}

__device__ __forceinline__ float fsig(float x) {
  float e = __expf(-x);                        // saturation-safe
  return __builtin_amdgcn_rcpf(1.0f + e);
}
__device__ __forceinline__ float ftanh(float x) {
  float ax = fabsf(x);
  float e  = __expf(-2.0f * ax);               // in (0,1] -> no overflow/NaN
  float r  = (1.0f - e) * __builtin_amdgcn_rcpf(1.0f + e);
  return copysignf(r, x);
}
__device__ __forceinline__ float qsum(float v) {
  v += __int_as_float(__builtin_amdgcn_update_dpp(
        0, __float_as_int(v), 0xB1, 0xF, 0xF, false)); // [1,0,3,2]
  v += __int_as_float(__builtin_amdgcn_update_dpp(
        0, __float_as_int(v), 0x4E, 0xF, 0xF, false)); // [2,3,0,1]
  return v;
}
// wave 0 polls 64 flags; others park at the barrier.
__device__ __forceinline__ void wait1(int* f, int tid, int target) {
  if (tid < 64) {
    while (true) {
      int v = __hip_atomic_load(&f[tid], __ATOMIC_RELAXED, __HIP_MEMORY_SCOPE_AGENT);
      if (__ballot(v < target) == 0ull) break;
      __builtin_amdgcn_s_sleep(2);
    }
  }
  __syncthreads();
  asm volatile("" ::: "memory");   // compiler barrier: no hoisting data loads
}

extern "C" __global__ void __launch_bounds__(NTHR, 1)
lstm_persistent(const float* __restrict__ y,
                const float* __restrict__ Wih,
                const float* __restrict__ Whh,
                const float* __restrict__ bih,
                const float* __restrict__ bhh,
                const float* __restrict__ Whr,
                const int*   __restrict__ mslp,
                float*       __restrict__ out,
                float*       __restrict__ hbuf,
                float*       __restrict__ actg,
                int*         __restrict__ hflag,
                int*         __restrict__ pflag)
{
  extern __shared__ float lds[];
  float* Ws   = lds;
  float* XH   = lds + LDS_W;
  float* ACT  = XH + LDS_XH;
  float* PRJ  = XH;                 // proj arena: 4896 floats over XH+ACT

  const int bid = blockIdx.x;
  const int l   = (bid & 7) >> 1;   // layer on XCD pair {2l,2l+1}
  const int w   = ((bid & 1)) + 2 * (bid >> 3);   // 0..63, bijective
  const int J0  = w * 16;
  const int tid  = threadIdx.x;
  const int msl  = mslp[0];

  // ---- one-time: gate-weight slice (k-major, swizzled) into LDS -----------
  {
    const float* wih_l = Wih + (size_t)l * G4_ * P_;
    const float* whh_l = Whh + (size_t)l * G4_ * P_;
    for (int it = 0; it < 32; ++it) {
      int idx4 = tid + NTHR * it;            // 8192 F4 total
      int r    = idx4 >> 7;                  // 0..63, r = 4*cell + gate
      int k4   = (idx4 & 127) << 2;          // 0..508
      int g = r & 3, j = r >> 2;
      int grow = g * H_ + J0 + j;            // torch gate order i,f,g,o
      F4 v;
      if (k4 < 256) v = *(const F4*)&wih_l[(size_t)grow * P_ + k4];
      else          v = *(const F4*)&whh_l[(size_t)grow * P_ + (k4 - 256)];
#pragma unroll
      for (int i = 0; i < 4; ++i)
        Ws[(size_t)(k4 + i) * 64 + (r ^ (4 * (i & 1)))] = v.f[i];
    }
  }
  __syncthreads();

  // ---- thread mappings ----------------------------------------------------
  const int w4   = tid >> 6;            // wave 0..3
  const int lane = tid & 63;
  const int c16  = lane >> 2;           // 0..15
  const int ksub = lane & 3;            // k-split lane within quad
  const int lr   = (w4 << 1) | (c16 >> 3);   // rows 8lr..8lr+7
  const int lb   = c16 & 7;                  // b 8lb..8lb+7
  const int swz  = 4 * (ksub & 1);
  // GEMM staging (transpose path, layer-0 y):
  const int sb0 = tid >> 3, skq = tid & 7, skl = skq << 2;
  // GEMM staging (fast path, h ring [p][b]):
  const int kidx = tid >> 3, bq = tid & 7;
  // act repack / proj staging:
  const int jqr = tid >> 6, b_r = tid & 63;
  // proj compute:
  const int b_p = (w4 << 4) | (tid & 15);
  const int pw  = (tid >> 4) & 3;
  // proj Whr staging (wave 0 lanes 0..31 only, as in R3):
  const int pws = tid >> 3, jqlw = tid & 7;   // valid when tid < 32

  float* hsrc = hbuf + (size_t)l * (WWIN * HSLOT);
  const float* hprv = (l > 0) ? (hbuf + (size_t)(l - 1) * (WWIN * HSLOT)) : hbuf;
  float* AGf = actg + (size_t)l * H_ * B_;   // [jq 0..255][b 0..63] of 4 floats

  // bias straight to registers (own 8 rows)
  float biasr[8];
#pragma unroll
  for (int i = 0; i < 8; ++i) {
    int r = 8 * lr + i, g = r & 3, j = r >> 2;
    int grow = g * H_ + J0 + j;
    biasr[i] = bih[l * G4_ + grow] + bhh[l * G4_ + grow];
  }

  float cst[2][2] = {{0.f, 0.f}, {0.f, 0.f}};

  for (int t = 0; t < T_; ++t) {
    float acc[8][8];
#pragma unroll
    for (int i = 0; i < 8; ++i)
#pragma unroll
      for (int jx = 0; jx < 8; ++jx) acc[i][jx] = 0.f;

    auto gemm_chunk = [&](int cc) {
      const float* buf = XH + ((cc & 1) << 11);
      const int kb = cc << 5;
#pragma unroll
      for (int jj = 0; jj < 8; ++jj) {
        const int kl = 4 * jj + ksub;
        const float* wrow = Ws + (size_t)(kb + kl) * 64;
        F4 wlo = *(const F4*)&wrow[(8 * lr) ^ swz];
        F4 whi = *(const F4*)&wrow[(8 * lr + 4) ^ swz];
        const int sx = (4 * jj) ^ swz;                  // kl&28 = 4*jj
        const float* xrow = buf + kl * 64;
        F4 xlo = *(const F4*)&xrow[(8 * lb) ^ sx];
        F4 xhi = *(const F4*)&xrow[(8 * lb + 4) ^ sx];
#pragma unroll
        for (int i = 0; i < 4; ++i)
#pragma unroll
          for (int jx = 0; jx < 4; ++jx) {
            acc[i][jx]         = fmaf(wlo.f[i], xlo.f[jx], acc[i][jx]);
            acc[i][jx + 4]     = fmaf(wlo.f[i], xhi.f[jx], acc[i][jx + 4]);
            acc[i + 4][jx]     = fmaf(whi.f[i], xlo.f[jx], acc[i + 4][jx]);
            acc[i + 4][jx + 4] = fmaf(whi.f[i], xhi.f[jx], acc[i + 4][jx + 4]);
          }
      }
    };

    // ---- h-ring staging: issue (agent loads -> regs), commit (regs -> LDS)
    float rg[8];
    auto ring_issue = [&](const float* src, int cc) {
      const int koff = (cc & 7) << 5;
      const float* pb = src + (size_t)(koff + kidx) * 64 + 4 * bq;
#pragma unroll
      for (int i = 0; i < 4; ++i) rg[i]     = lda(pb + i);
#pragma unroll
      for (int i = 0; i < 4; ++i) rg[4 + i] = lda(pb + 32 + i);
    };
    auto ring_commit = [&](float* dst) {
      const int sx = (kidx & 28) ^ (4 * (kidx & 1));
      const int cA = (4 * bq) ^ sx, cB = (4 * bq + 32) ^ sx;
#pragma unroll
      for (int i = 0; i < 4; ++i) dst[kidx * 64 + cA + i] = rg[i];
#pragma unroll
      for (int i = 0; i < 4; ++i) dst[kidx * 64 + cB + i] = rg[4 + i];
    };
    // layer-0 y staging (plain cached loads, transpose)
    auto stage_y = [&](int cc, float* dst) {
      const int koff = (cc & 7) << 5;
      F4 ra  = *(const F4*)(y + ((size_t)sb0 * T_ + t) * P_ + koff + skl);
      F4 rb4 = *(const F4*)(y + ((size_t)(sb0 + 32) * T_ + t) * P_ + koff + skl);
#pragma unroll
      for (int i2 = 0; i2 < 4; ++i2) {
        const int sw = (skq << 2) ^ (4 * (i2 & 1));
        dst[(skl + i2) * 64 + (sb0 ^ sw)]        = ra.f[i2];
        dst[(skl + i2) * 64 + ((sb0 + 32) ^ sw)] = rb4.f[i2];
      }
    };

    // ---- x-half of gate GEMM ---------------------------------------------
    if (l > 0) wait1(hflag + (l - 1) * 64, tid, t);
    if (l == 0) {
      stage_y(0, XH);
      __syncthreads();
      for (int cc = 0; cc < 8; ++cc) {
        if (cc < 7) stage_y(cc + 1, XH + (((cc + 1) & 1) << 11));
        gemm_chunk(cc);
        __syncthreads();
      }
    } else {
      const float* xp = hprv + (size_t)(t & (WWIN - 1)) * HSLOT;
      ring_issue(xp, 0);
      ring_commit(XH);
      __syncthreads();
      for (int cc = 0; cc < 8; ++cc) {
        if (cc < 7) ring_issue(xp, cc + 1);
        gemm_chunk(cc);
        if (cc < 7) ring_commit(XH + (((cc + 1) & 1) << 11));
        __syncthreads();
      }
    }
    // ---- h-half (recurrent critical path) --------------------------------
    if (t > 0) {
      wait1(hflag + l * 64, tid, t - 1);
      const float* hp = hsrc + (size_t)((t - 1) & (WWIN - 1)) * HSLOT;
      ring_issue(hp, 8);
      ring_commit(XH);
      __syncthreads();
      for (int cc = 8; cc < 16; ++cc) {
        if (cc < 15) ring_issue(hp, cc + 1);
        gemm_chunk(cc);
        if (cc < 15) ring_commit(XH + (((cc + 1) & 1) << 11));
        __syncthreads();
      }
    }

    // ---- combine k-split partials across lane quads (VALU-only) ----------
#pragma unroll
    for (int i = 0; i < 8; ++i)
#pragma unroll
      for (int jx = 0; jx < 8; ++jx) acc[i][jx] = qsum(acc[i][jx]);

    // ---- activations + cell update ---------------------------------------
#pragma unroll
    for (int m = 0; m < 2; ++m)
#pragma unroll
      for (int n = 0; n < 2; ++n) {
#define MUX(I) ((ksub & 2) ? ((ksub & 1) ? acc[I][6 + n] : acc[I][4 + n])  \
                           : ((ksub & 1) ? acc[I][2 + n] : acc[I][0 + n]))
        float vi = MUX(4 * m + 0) + biasr[4 * m + 0];
        float vf = MUX(4 * m + 1) + biasr[4 * m + 1];
        float vg = MUX(4 * m + 2) + biasr[4 * m + 2];
        float vo = MUX(4 * m + 3) + biasr[4 * m + 3];
#undef MUX
        float ig = fsig(vi), fg = fsig(vf), gg = ftanh(vg), og = fsig(vo);
        float cn = fmaf(fg, cst[m][n], ig * gg);
        cst[m][n] = cn;
        ACT[(2 * lr + m) * 64 + (8 * lb + 2 * ksub + n)] = og * ftanh(cn);
      }
    __syncthreads();

    // ---- broadcast acts: LDS -> global [jq][b][4], agent stores ----------
    {
      float* dst = AGf + ((size_t)(4 * w + jqr) * 64 + b_r) * 4;
#pragma unroll
      for (int u = 0; u < 4; ++u) sta(dst + u, ACT[(4 * jqr + u) * 64 + b_r]);
    }
    drain_vm();          // release: own stores complete at coherence point
    __syncthreads();     // all waves drained
    if (tid == 0)
      __hip_atomic_store(&pflag[l * 64 + w], t, __ATOMIC_RELAXED, __HIP_MEMORY_SCOPE_AGENT);

    // ---- projection: h[b][4w+pw] = sum_j act[j][b]*Whr[4w+pw][j] ---------
    wait1(pflag + l * 64, tid, t);

    float ar[8]; F4 wr;
    auto proj_issue = [&](int ch) {
      const float* a0 = AGf + ((size_t)(8 * ch + 2 * jqr) * 64 + b_r) * 4;
#pragma unroll
      for (int i = 0; i < 4; ++i) ar[i]     = lda(a0 + i);
#pragma unroll
      for (int i = 0; i < 4; ++i) ar[4 + i] = lda(a0 + 256 + i);
      if (tid < 32)      // Whr is read-only input: plain cached load
        wr = *(const F4*)(Whr + ((size_t)(l * P_ + 4 * w + pws)) * H_
                          + 32 * ch + 4 * jqlw);
    };
    auto proj_commit = [&](int ch) {
      float* ab = PRJ + (ch & 1) * PA_BUF;
#pragma unroll
      for (int i = 0; i < 4; ++i) ab[b_r * PA_CH + 4 * (2 * jqr) + i]     = ar[i];
#pragma unroll
      for (int i = 0; i < 4; ++i) ab[b_r * PA_CH + 4 * (2 * jqr + 1) + i] = ar[4 + i];
      if (tid < 32)
        *(F4*)&(PRJ + PW_OFF + (ch & 1) * PW_BUF)[pws * PA_CH + 4 * jqlw] = wr;
    };

    float s = 0.f;
    proj_issue(0);
    proj_commit(0);
    __syncthreads();
    for (int ch = 0; ch < 32; ++ch) {
      if (ch < 31) proj_issue(ch + 1);         // loads in flight over compute
      const float* ab = PRJ + (ch & 1) * PA_BUF + b_p * PA_CH;
      const float* wb = PRJ + PW_OFF + (ch & 1) * PW_BUF + pw * PA_CH;
#pragma unroll
      for (int jj = 0; jj < 8; ++jj) {
        F4 a  = *(const F4*)&ab[4 * jj];
        F4 wv = *(const F4*)&wb[4 * jj];
        s = fmaf(a.f[0], wv.f[0], s);
        s = fmaf(a.f[1], wv.f[1], s);
        s = fmaf(a.f[2], wv.f[2], s);
        s = fmaf(a.f[3], wv.f[3], s);
      }
      if (ch < 31) proj_commit(ch + 1);        // compiler waits here, not above
      __syncthreads();
    }

    // ---- emit h (ring, agent store) + output -----------------------------
    if (l < 3) wait1(hflag + (l + 1) * 64, tid, t - WWIN);   // ring back-pressure
    sta(hsrc + (size_t)(t & (WWIN - 1)) * HSLOT + (size_t)(4 * w + pw) * 64 + b_p, s);
    if (l == 3 && t >= msl)
      out[((size_t)b_p * (T_ - msl) + (t - msl)) * P_ + 4 * w + pw] = s;
    drain_vm();          // release h
    __syncthreads();
    if (tid == 0)
      __hip_atomic_store(&hflag[l * 64 + w], t, __ATOMIC_RELAXED, __HIP_MEMORY_SCOPE_AGENT);
  }
}

extern "C" void kernel_launch(void* const* d_in, const int* in_sizes, int n_in,
                              void* d_out, int out_size, void* d_ws, size_t ws_size,
                              hipStream_t stream) {
  const float* y   = (const float*)d_in[0];
  const float* Wih = (const float*)d_in[1];
  const float* Whh = (const float*)d_in[2];
  const float* bih = (const float*)d_in[3];
  const float* bhh = (const float*)d_in[4];
  const float* Whr = (const float*)d_in[5];
  const int*   msl = (const int*)d_in[6];
  float* out = (float*)d_out;

  // ws: [flags 4KB][act broadcast 1MB][h ring 2MB]  (~3 MB total)
  char*  ws    = (char*)d_ws;
  int*   flags = (int*)ws;
  float* actg  = (float*)(ws + 4096);
  float* hbuf  = (float*)(ws + 4096 + ACT_FLOATS * sizeof(float));

  hipMemsetAsync(flags, 0xFF, 4096, stream);   // epoch counters start at -1

  hipFuncSetAttribute(reinterpret_cast<const void*>(&lstm_persistent),
                      hipFuncAttributeMaxDynamicSharedMemorySize, LDS_BYTES);

  lstm_persistent<<<dim3(L_ * 64), dim3(NTHR), LDS_BYTES, stream>>>(
      y, Wih, Whh, bih, bhh, Whr, msl, out,
      hbuf, actg, flags /*hflag*/, flags + 256 /*pflag*/);
}